// Round 11
// baseline (192.135 us; speedup 1.0000x reference)
//
#include <hip/hip_runtime.h>
#include <hip/hip_bf16.h>

// Problem constants
#define B_  4096
#define T_  80
#define E_  100
#define U_  64
#define G_  256    // 4*U
#define V_  10000

#define TP   81    // tokLDS row stride (ints)
#define HS   72    // hX row stride (bf16): 144B rows, 16B aligned
#define AS   136   // embk A-tile LDS stride (bf16)

typedef __attribute__((ext_vector_type(8))) __bf16 bf16x8;
typedef __attribute__((ext_vector_type(4))) __bf16 bf16x4;
typedef __attribute__((ext_vector_type(4))) float  floatx4;

__device__ __forceinline__ float sigmoidf_(float x) {
    return __fdividef(1.f, 1.f + __expf(-x));
}

// LSTM cell, shared-rcp fused activations (4 exp + 3 rcp):
__device__ __forceinline__ float cell_(float zi, float zf, float zg, float zo,
                                       float& c) {
    float ei = __expf(-zi);
    float eg = __expf(2.f * zg);
    float Ai = 1.f + ei, Bg = 1.f + eg;
    float rig = __builtin_amdgcn_rcpf(Ai * Bg);
    float term1 = (rig * Bg) * fmaf(-2.f, rig * Ai, 1.f);   // sigma(zi)*tanh(zg)
    float sf = __builtin_amdgcn_rcpf(1.f + __expf(-zf));    // sigma(zf)
    float cn = fmaf(sf, c, term1);
    float eo = __expf(-zo);
    float ec = __expf(2.f * cn);
    float Ao = 1.f + eo, Bc = 1.f + ec;
    float roc = __builtin_amdgcn_rcpf(Ao * Bc);
    float hn = (roc * Bc) * fmaf(-2.f, roc * Ao, 1.f);      // sigma(zo)*tanh(cn)
    c = cn;
    return hn;
}

// ---------------------------------------------------------------------------
// Kernel A (MFMA): embk[v][g] = b1[g] + emb[v] . k1[:,g]  (R3 version)
// ---------------------------------------------------------------------------
__global__ __launch_bounds__(256) void embk_kernel(const float* __restrict__ emb,
                                                   const float* __restrict__ k1,
                                                   const float* __restrict__ b1,
                                                   float* __restrict__ embk) {
    __shared__ __bf16 aLDS[64 * AS];

    const int tid  = threadIdx.x;
    const int lane = tid & 63;
    const int w    = tid >> 6;
    const int n    = lane & 15;
    const int kg   = lane >> 4;
    const int v0   = blockIdx.x * 64;
    const int nrows = min(64, V_ - v0);

    for (int i = tid; i < 64 * 28; i += 256) {
        int r = i / 28, e = 100 + (i - r * 28);
        aLDS[r * AS + e] = (__bf16)0.f;
    }
    for (int i = tid; i < nrows * E_; i += 256) {
        int r = i / E_, e = i - r * E_;
        aLDS[r * AS + e] = (__bf16)emb[(long)v0 * E_ + i];
    }

    bf16x8 bfr[4][4];
#pragma unroll
    for (int ct = 0; ct < 4; ++ct)
#pragma unroll
        for (int kc = 0; kc < 4; ++kc) {
            bf16x8 s;
#pragma unroll
            for (int jj = 0; jj < 8; ++jj) {
                int k = kc * 32 + kg * 8 + jj;
                s[jj] = (k < E_) ? (__bf16)k1[k * G_ + w * 64 + ct * 16 + n]
                                 : (__bf16)0.f;
            }
            bfr[ct][kc] = s;
        }

    float bv0 = b1[w * 64 +  0 + n];
    float bv1 = b1[w * 64 + 16 + n];
    float bv2 = b1[w * 64 + 32 + n];
    float bv3 = b1[w * 64 + 48 + n];

    __syncthreads();

#pragma unroll
    for (int mt = 0; mt < 4; ++mt) {
        const __bf16* ab = aLDS + (mt * 16 + n) * AS + kg * 8;
        bf16x8 a0 = *(const bf16x8*)(ab + 0 * 32);
        bf16x8 a1 = *(const bf16x8*)(ab + 1 * 32);
        bf16x8 a2 = *(const bf16x8*)(ab + 2 * 32);
        bf16x8 a3 = *(const bf16x8*)(ab + 3 * 32);
#pragma unroll
        for (int ct = 0; ct < 4; ++ct) {
            float bv = (ct == 0) ? bv0 : (ct == 1) ? bv1 : (ct == 2) ? bv2 : bv3;
            floatx4 acc = {bv, bv, bv, bv};
            acc = __builtin_amdgcn_mfma_f32_16x16x32_bf16(a0, bfr[ct][0], acc, 0, 0, 0);
            acc = __builtin_amdgcn_mfma_f32_16x16x32_bf16(a1, bfr[ct][1], acc, 0, 0, 0);
            acc = __builtin_amdgcn_mfma_f32_16x16x32_bf16(a2, bfr[ct][2], acc, 0, 0, 0);
            acc = __builtin_amdgcn_mfma_f32_16x16x32_bf16(a3, bfr[ct][3], acc, 0, 0, 0);
#pragma unroll
            for (int r = 0; r < 4; ++r) {
                int v = v0 + mt * 16 + kg * 4 + r;
                if (v < V_) embk[(long)v * G_ + w * 64 + ct * 16 + n] = acc[r];
            }
        }
    }
}

// ---------------------------------------------------------------------------
// Kernel B: WAVE-AUTONOMOUS recurrence. 256 blocks x 64 threads = one wave
// per block per CU. The wave owns 16 batch rows for all 80 steps: it computes
// the FULL z^T[256 x 16] = r1^T @ h^T + xk itself (16 M-tiles x 2 MFMAs,
// A = r1^T static in 128 VGPRs, xk prefetched as C-init). C/D layout gives
// lane (n,kg) all 4 gates of units {16q+4kg+r} of row n -> 16 dense
// cells/lane. h (16 bf16/lane) round-trips through WAVE-PRIVATE LDS to
// re-enter as B-fragments. ZERO barriers, ZERO cross-wave traffic: the
// per-step s_barrier rendezvous (the hypothesized ~2500-cyc floor) is gone.
// Single-buffered hX is safe: a wave's DS ops complete in issue order, so
// this step's B-reads can't be passed by this step's h-writes.
// ---------------------------------------------------------------------------
__global__ __launch_bounds__(64, 1) void lstm_kernel(const int*   __restrict__ tokens,
                                                     const float* __restrict__ embk,
                                                     const float* __restrict__ r1,
                                                     const float* __restrict__ Wd,
                                                     const float* __restrict__ bd,
                                                     float* __restrict__ out) {
    __shared__ int    tokLDS[16 * TP];       // 5.2 KB
    __shared__ __bf16 hX[16 * HS];           // 2.3 KB bounce buffer (wave-private)

    const int lane = threadIdx.x;            // 0..63
    const int n    = lane & 15;              // batch row (N-operand / A m-index)
    const int kg   = lane >> 4;              // 0..3
    const int bb   = blockIdx.x * 16;

    for (int i = lane; i < 16 * T_; i += 64) {
        int r = i / T_, t = i - r * T_;
        tokLDS[r * TP + t] = tokens[bb * T_ + i];
    }
    for (int i = lane; i < 16 * HS; i += 64) hX[i] = (__bf16)0.f;  // h_{-1} = 0

    // A = r1^T fragments (static, 128 VGPRs): tile ct = gate-cols
    // [ct*16, ct*16+16); A[m=n][k = kc*32 + kg*8 + jj] = r1[k][ct*16 + n]
    bf16x8 afr[16][2];
#pragma unroll
    for (int ct = 0; ct < 16; ++ct)
#pragma unroll
        for (int kc = 0; kc < 2; ++kc) {
            bf16x8 s;
#pragma unroll
            for (int jj = 0; jj < 8; ++jj)
                s[jj] = (__bf16)r1[(kc * 32 + kg * 8 + jj) * G_ + ct * 16 + n];
            afr[ct][kc] = s;
        }

    // cell state: 16 cells/lane: (row n, unit 16q + 4kg + r)
    float c[4][4];
#pragma unroll
    for (int q = 0; q < 4; ++q)
#pragma unroll
        for (int r = 0; r < 4; ++r) c[q][r] = 0.f;

    // xk C-init prefetch for t=0: xc[ct] = embk[tok[n][0]][ct*16 + kg*4 ..+3]
    floatx4 xc[16];
    {
        // tokLDS write above is this wave's own; in-order DS => read-after-write ok
        const float* base = embk + (long)tokLDS[n * TP + 0] * G_ + kg * 4;
#pragma unroll
        for (int ct = 0; ct < 16; ++ct)
            xc[ct] = *(const floatx4*)(base + ct * 16);
    }

    for (int t = 0; t < T_; ++t) {
        // B = h^T_{t-1} from wave-private LDS
        bf16x8 hb0 = *(const bf16x8*)(hX + n * HS + kg * 8);
        bf16x8 hb1 = *(const bf16x8*)(hX + n * HS + 32 + kg * 8);

        // z^T tiles, acc in place over the prefetched C-init
        floatx4 z[16];
#pragma unroll
        for (int ct = 0; ct < 16; ++ct) {
            floatx4 a = xc[ct];
            a = __builtin_amdgcn_mfma_f32_16x16x32_bf16(afr[ct][0], hb0, a, 0, 0, 0);
            a = __builtin_amdgcn_mfma_f32_16x16x32_bf16(afr[ct][1], hb1, a, 0, 0, 0);
            z[ct] = a;
        }

        // prefetch xk for t+1 (in flight under the gate math below)
        {
            const int tt = (t + 1 < T_) ? (t + 1) : (T_ - 1);
            const float* base = embk + (long)tokLDS[n * TP + tt] * G_ + kg * 4;
#pragma unroll
            for (int ct = 0; ct < 16; ++ct)
                xc[ct] = *(const floatx4*)(base + ct * 16);
        }

        // gates: 16 cells/lane. Unit u = 16q + 4kg + r:
        //   zi = z[q][r], zf = z[4+q][r], zg = z[8+q][r], zo = z[12+q][r]
        // h output: 4 consecutive units per q -> one b64 LDS write each.
#pragma unroll
        for (int q = 0; q < 4; ++q) {
            bf16x4 hv;
#pragma unroll
            for (int r = 0; r < 4; ++r) {
                float hn = cell_(z[q][r], z[4 + q][r], z[8 + q][r], z[12 + q][r],
                                 c[q][r]);
                hv[r] = (__bf16)hn;
            }
            *(bf16x4*)(hX + n * HS + 16 * q + 4 * kg) = hv;
        }
        // no barrier: next iteration's DS reads are ordered behind these DS
        // writes by the wave's in-order LDS queue (lgkmcnt inserted by compiler)
    }

    // out[b] = sigmoid(h_79[b] . Wd + bd)
    // lane (n,kg) sums units [kg*16, kg*16+16) of row n, then reduce over kg
    {
        float s = 0.f;
#pragma unroll
        for (int u = 0; u < 16; ++u)
            s = fmaf((float)hX[n * HS + kg * 16 + u], Wd[kg * 16 + u], s);
        s += __shfl_down(s, 32);
        s += __shfl_down(s, 16);
        if (lane < 16) out[bb + n] = sigmoidf_(s + bd[0]);
    }
}

// ---------------------------------------------------------------------------
extern "C" void kernel_launch(void* const* d_in, const int* in_sizes, int n_in,
                              void* d_out, int out_size, void* d_ws, size_t ws_size,
                              hipStream_t stream) {
    const int*   tokens = (const int*)  d_in[0];
    const float* emb    = (const float*)d_in[1];
    // d_in[2..4] = k0, r0, b0 : dead in the reference (cell0 state unused)
    const float* k1     = (const float*)d_in[5];
    const float* r1     = (const float*)d_in[6];
    const float* b1     = (const float*)d_in[7];
    const float* Wd     = (const float*)d_in[8];
    const float* bd     = (const float*)d_in[9];
    float*       out    = (float*)d_out;

    float* embk = (float*)d_ws;              // V_*G_ floats = 10.24 MB

    embk_kernel<<<(V_ + 63) / 64, 256, 0, stream>>>(emb, k1, b1, embk);
    lstm_kernel<<<B_ / 16, 64, 0, stream>>>(tokens, embk, r1, Wd, bd, out);
}

// Round 12
// 164.545 us; speedup vs baseline: 1.1677x; 1.1677x over previous
//
#include <hip/hip_runtime.h>
#include <hip/hip_bf16.h>

// Problem constants
#define B_  4096
#define T_  80
#define E_  100
#define U_  64
#define G_  256    // 4*U
#define V_  10000

#define ZS   264   // zB row stride (floats): <=2-way on masked scatter
#define HS   72    // hX row stride (bf16): 144B rows, 16B aligned
#define AS   136   // embk A-tile LDS stride (bf16)

typedef __attribute__((ext_vector_type(8))) __bf16 bf16x8;
typedef __attribute__((ext_vector_type(4))) __bf16 bf16x4;
typedef __attribute__((ext_vector_type(4))) float  floatx4;

__device__ __forceinline__ float sigmoidf_(float x) {
    return __fdividef(1.f, 1.f + __expf(-x));
}

// LSTM cell, shared-rcp fused activations (4 exp + 3 rcp):
__device__ __forceinline__ float cell_(float zi, float zf, float zg, float zo,
                                       float& c) {
    float ei = __expf(-zi);
    float eg = __expf(2.f * zg);
    float Ai = 1.f + ei, Bg = 1.f + eg;
    float rig = __builtin_amdgcn_rcpf(Ai * Bg);
    float term1 = (rig * Bg) * fmaf(-2.f, rig * Ai, 1.f);   // sigma(zi)*tanh(zg)
    float sf = __builtin_amdgcn_rcpf(1.f + __expf(-zf));    // sigma(zf)
    float cn = fmaf(sf, c, term1);
    float eo = __expf(-zo);
    float ec = __expf(2.f * cn);
    float Ao = 1.f + eo, Bc = 1.f + ec;
    float roc = __builtin_amdgcn_rcpf(Ao * Bc);
    float hn = (roc * Bc) * fmaf(-2.f, roc * Ao, 1.f);      // sigma(zo)*tanh(cn)
    c = cn;
    return hn;
}

// ---------------------------------------------------------------------------
// Kernel A (MFMA): embk[v][g] = b1[g] + emb[v] . k1[:,g]  (R3 version)
// ---------------------------------------------------------------------------
__global__ __launch_bounds__(256) void embk_kernel(const float* __restrict__ emb,
                                                   const float* __restrict__ k1,
                                                   const float* __restrict__ b1,
                                                   float* __restrict__ embk) {
    __shared__ __bf16 aLDS[64 * AS];

    const int tid  = threadIdx.x;
    const int lane = tid & 63;
    const int w    = tid >> 6;
    const int n    = lane & 15;
    const int kg   = lane >> 4;
    const int v0   = blockIdx.x * 64;
    const int nrows = min(64, V_ - v0);

    for (int i = tid; i < 64 * 28; i += 256) {
        int r = i / 28, e = 100 + (i - r * 28);
        aLDS[r * AS + e] = (__bf16)0.f;
    }
    for (int i = tid; i < nrows * E_; i += 256) {
        int r = i / E_, e = i - r * E_;
        aLDS[r * AS + e] = (__bf16)emb[(long)v0 * E_ + i];
    }

    bf16x8 bfr[4][4];
#pragma unroll
    for (int ct = 0; ct < 4; ++ct)
#pragma unroll
        for (int kc = 0; kc < 4; ++kc) {
            bf16x8 s;
#pragma unroll
            for (int jj = 0; jj < 8; ++jj) {
                int k = kc * 32 + kg * 8 + jj;
                s[jj] = (k < E_) ? (__bf16)k1[k * G_ + w * 64 + ct * 16 + n]
                                 : (__bf16)0.f;
            }
            bfr[ct][kc] = s;
        }

    float bv0 = b1[w * 64 +  0 + n];
    float bv1 = b1[w * 64 + 16 + n];
    float bv2 = b1[w * 64 + 32 + n];
    float bv3 = b1[w * 64 + 48 + n];

    __syncthreads();

#pragma unroll
    for (int mt = 0; mt < 4; ++mt) {
        const __bf16* ab = aLDS + (mt * 16 + n) * AS + kg * 8;
        bf16x8 a0 = *(const bf16x8*)(ab + 0 * 32);
        bf16x8 a1 = *(const bf16x8*)(ab + 1 * 32);
        bf16x8 a2 = *(const bf16x8*)(ab + 2 * 32);
        bf16x8 a3 = *(const bf16x8*)(ab + 3 * 32);
#pragma unroll
        for (int ct = 0; ct < 4; ++ct) {
            float bv = (ct == 0) ? bv0 : (ct == 1) ? bv1 : (ct == 2) ? bv2 : bv3;
            floatx4 acc = {bv, bv, bv, bv};
            acc = __builtin_amdgcn_mfma_f32_16x16x32_bf16(a0, bfr[ct][0], acc, 0, 0, 0);
            acc = __builtin_amdgcn_mfma_f32_16x16x32_bf16(a1, bfr[ct][1], acc, 0, 0, 0);
            acc = __builtin_amdgcn_mfma_f32_16x16x32_bf16(a2, bfr[ct][2], acc, 0, 0, 0);
            acc = __builtin_amdgcn_mfma_f32_16x16x32_bf16(a3, bfr[ct][3], acc, 0, 0, 0);
#pragma unroll
            for (int r = 0; r < 4; ++r) {
                int v = v0 + mt * 16 + kg * 4 + r;
                if (v < V_) embk[(long)v * G_ + w * 64 + ct * 16 + n] = acc[r];
            }
        }
    }
}

// ---------------------------------------------------------------------------
// Kernel B: 4-ROW WAVE-AUTONOMOUS recurrence. 1024 blocks x 64 thr = 4
// waves/CU (one per SIMD), ZERO barriers. Each wave owns 4 batch rows for
// all 80 steps: computes the full z^T[256 x N] = r1^T @ h^T itself (16
// M-tiles x 2 MFMAs; B rows replicated n&3, dead cols discarded), scatters
// the 4 live rows' z to WAVE-PRIVATE LDS (masked, ~2-way), reads back
// BALANCED (lane -> row lane&3, units 4*(lane>>2)) so all 64 lanes do
// exactly 4 cells of gate math -- the trans-issue bound now spreads over
// all 1024 SIMDs instead of 256. xk added post-bounce from a 1-step
// register prefetch. In-order per-wave DS ops make the barrier-free LDS
// round-trip safe (HW-verified by R10's passing run).
// ---------------------------------------------------------------------------
__global__ __launch_bounds__(64) void lstm_kernel(const int*   __restrict__ tokens,
                                                  const float* __restrict__ embk,
                                                  const float* __restrict__ r1,
                                                  const float* __restrict__ Wd,
                                                  const float* __restrict__ bd,
                                                  float* __restrict__ out) {
    __shared__ int    tokLDS[4 * T_];        // 1.28 KB
    __shared__ float  zB[4 * ZS];            // 4.2 KB  z bounce (live rows only)
    __shared__ __bf16 hX[4 * HS];            // 0.58 KB h round-trip

    const int lane = threadIdx.x;            // 0..63
    const int n    = lane & 15;              // MFMA N / A m-index
    const int kg   = lane >> 4;              // 0..3
    const int bb   = blockIdx.x * 4;
    const int crow = lane & 3;               // gate-phase row
    const int u0   = (lane >> 2) * 4;        // gate-phase unit base (0..60)

    for (int i = lane; i < 4 * T_; i += 64) tokLDS[i] = tokens[bb * T_ + i];
    for (int i = lane; i < 4 * HS; i += 64) hX[i] = (__bf16)0.f;   // h_{-1}=0

    // A = r1^T fragments (static, 128 VGPRs): tile ct = gate-cols
    // [ct*16, ct*16+16); A[m=n][k = kc*32 + kg*8 + jj] = r1[k][ct*16 + n]
    bf16x8 afr[16][2];
#pragma unroll
    for (int ct = 0; ct < 16; ++ct)
#pragma unroll
        for (int kc = 0; kc < 2; ++kc) {
            bf16x8 s;
#pragma unroll
            for (int jj = 0; jj < 8; ++jj)
                s[jj] = (__bf16)r1[(kc * 32 + kg * 8 + jj) * G_ + ct * 16 + n];
            afr[ct][kc] = s;
        }

    float c[4]    = {0.f, 0.f, 0.f, 0.f};    // cell state (row crow, unit u0+j)
    float hfin[4] = {0.f, 0.f, 0.f, 0.f};

    // xk register prefetch (1 step deep): xk*[g] = embk[tok][g*64 + u0 ..+3]
    floatx4 xkA[4], xkB[4];
    {
        const float* base = embk + (long)tokLDS[crow * T_ + 0] * G_ + u0;
#pragma unroll
        for (int g = 0; g < 4; ++g) xkA[g] = *(const floatx4*)(base + g * 64);
    }

    auto step = [&](int t, floatx4* use, floatx4* pf) {
        // prefetch xk for t+1 FIRST (in flight through MFMA + bounce + gates)
        {
            const int tt = (t + 1 < T_) ? (t + 1) : (T_ - 1);
            const float* base = embk + (long)tokLDS[crow * T_ + tt] * G_ + u0;
#pragma unroll
            for (int g = 0; g < 4; ++g) pf[g] = *(const floatx4*)(base + g * 64);
        }

        // B = h^T_{t-1}, rows replicated n&3 (cols n>=4 computed then dropped)
        bf16x8 hb0 = *(const bf16x8*)(hX + crow * HS + kg * 8);
        bf16x8 hb1 = *(const bf16x8*)(hX + crow * HS + 32 + kg * 8);

        floatx4 z[16];
#pragma unroll
        for (int ct = 0; ct < 16; ++ct) {
            floatx4 a = {0.f, 0.f, 0.f, 0.f};
            a = __builtin_amdgcn_mfma_f32_16x16x32_bf16(afr[ct][0], hb0, a, 0, 0, 0);
            a = __builtin_amdgcn_mfma_f32_16x16x32_bf16(afr[ct][1], hb1, a, 0, 0, 0);
            z[ct] = a;
        }

        // scatter live rows' z: zB[n][gatecol], gatecol = ct*16 + kg*4 + r
        if (n < 4) {
#pragma unroll
            for (int ct = 0; ct < 16; ++ct)
                *(floatx4*)(zB + n * ZS + ct * 16 + kg * 4) = z[ct];
        }
        __builtin_amdgcn_wave_barrier();     // pin DS write->read order

        // balanced gather: cell (crow, u0+j), gate g at zB[crow][g*64+u0+j]
        floatx4 zg[4];
#pragma unroll
        for (int g = 0; g < 4; ++g)
            zg[g] = *(const floatx4*)(zB + crow * ZS + g * 64 + u0);

        bf16x4 hv;
#pragma unroll
        for (int j = 0; j < 4; ++j) {
            float hn = cell_(zg[0][j] + use[0][j], zg[1][j] + use[1][j],
                             zg[2][j] + use[2][j], zg[3][j] + use[3][j], c[j]);
            hfin[j] = hn;
            hv[j] = (__bf16)hn;
        }
        *(bf16x4*)(hX + crow * HS + u0) = hv;
        // no barrier: per-wave in-order DS ordering covers all hazards
    };

    for (int t = 0; t < T_; t += 2) {
        step(t,     xkA, xkB);
        step(t + 1, xkB, xkA);
    }

    // out[b] = sigmoid(h_79[b] . Wd + bd), using exact fp32 final h
    {
        floatx4 wv = *(const floatx4*)(Wd + u0);
        float s = 0.f;
#pragma unroll
        for (int j = 0; j < 4; ++j) s = fmaf(hfin[j], wv[j], s);
        s += __shfl_xor(s, 4);
        s += __shfl_xor(s, 8);
        s += __shfl_xor(s, 16);
        s += __shfl_xor(s, 32);
        if (lane < 4) out[bb + lane] = sigmoidf_(s + bd[0]);
    }
}

// ---------------------------------------------------------------------------
extern "C" void kernel_launch(void* const* d_in, const int* in_sizes, int n_in,
                              void* d_out, int out_size, void* d_ws, size_t ws_size,
                              hipStream_t stream) {
    const int*   tokens = (const int*)  d_in[0];
    const float* emb    = (const float*)d_in[1];
    // d_in[2..4] = k0, r0, b0 : dead in the reference (cell0 state unused)
    const float* k1     = (const float*)d_in[5];
    const float* r1     = (const float*)d_in[6];
    const float* b1     = (const float*)d_in[7];
    const float* Wd     = (const float*)d_in[8];
    const float* bd     = (const float*)d_in[9];
    float*       out    = (float*)d_out;

    float* embk = (float*)d_ws;              // V_*G_ floats = 10.24 MB

    embk_kernel<<<(V_ + 63) / 64, 256, 0, stream>>>(emb, k1, b1, embk);
    lstm_kernel<<<B_ / 4, 64, 0, stream>>>(tokens, embk, r1, Wd, bd, out);
}